// Round 2
// baseline (30172.147 us; speedup 1.0000x reference)
//
#include <hip/hip_runtime.h>
#include <math.h>

// Problem constants (fixed by setup_inputs)
constexpr int U      = 128;   // UNITS
constexpr int G4     = 512;   // 4*U gate width
constexpr int NCls   = 10;    // classes
constexpr int TSTEPS = 1000;
constexpr int BATCH  = 256;
constexpr int WH1L   = 64;    // Wh1 rows cached in LDS (128 KB)
// Streamed per step per thread: all Wx1 (128 rows) + Wh1 rows 64..127 (64 rows)
// = 192 dwords = 12 chunks of 16, 3-deep register rotation (48 VGPRs).
// VGPR budget: wh0r 128 + bufs 48 + ~55 state ≈ 231 of 256
// (amdgpu_waves_per_eu(2,2) pins the allocator to the 256-reg budget;
//  round-1's default heuristic capped at 128 and spilled wh0r -> 47 GB HBM).

__device__ __forceinline__ float sigm(float x) {
    return 1.0f / (1.0f + __expf(-x));
}

// k = time_gate(t, tau, s); floor-mod semantics matching jnp.mod
__device__ __forceinline__ float tgate(float t, float tau, float s) {
    float r = fmodf(t - s, tau);
    if (r < 0.0f) r += tau;
    const float phi = r / tau;
    return (phi < 0.025f) ? 40.0f * phi
         : (phi < 0.05f)  ? 2.0f - 40.0f * phi
         : 0.001f * phi;
}

// Issue 16 streamed weight loads for chunk K into register buffer BUF.
// idx < 128  -> Wx1 row idx;  idx in [128,192) -> Wh1 row (idx-64) (i.e. 64..127)
#define ISSUE(K, BUF) { \
    _Pragma("unroll") \
    for (int ii = 0; ii < 16; ++ii) { \
        const int idx_ = (K) * 16 + ii; \
        (BUF)[ii] = (idx_ < 128) ? wx1p[idx_ * G4] : wh1p[(idx_ - 64) * G4]; \
    } }

// Consume chunk K from BUF. Chunks 0..7: Wx1 rows 16K.. with gh0s broadcast
// (LayerNorm-folded: gh0s[u] = gamma[u]*h0[u]). Chunks 8..11: Wh1 upper rows
// with h1s broadcast.
#define CONSUME(K, BUF) { \
    if ((K) < 8) { \
        _Pragma("unroll") \
        for (int q = 0; q < 4; ++q) { \
            const float4 g4_ = *reinterpret_cast<const float4*>(&gh0s[16*(K) + 4*q]); \
            ax0 += g4_.x * (BUF)[4*q+0]; \
            ax1 += g4_.y * (BUF)[4*q+1]; \
            ax2 += g4_.z * (BUF)[4*q+2]; \
            ax3 += g4_.w * (BUF)[4*q+3]; \
        } \
    } else { \
        _Pragma("unroll") \
        for (int q = 0; q < 4; ++q) { \
            const float4 h4_ = *reinterpret_cast<const float4*>(&h1s[64 + 16*((K)-8) + 4*q]); \
            ah0 += h4_.x * (BUF)[4*q+0]; \
            ah1 += h4_.y * (BUF)[4*q+1]; \
            ah2 += h4_.z * (BUF)[4*q+2]; \
            ah3 += h4_.w * (BUF)[4*q+3]; \
        } \
    } }

__global__ __launch_bounds__(512, 2)
__attribute__((amdgpu_waves_per_eu(2, 2)))
void plstm_fused(
    const float* __restrict__ inputs,  // [B,T,3]
    const float* __restrict__ times,   // [B,T]
    const float* __restrict__ Wx0,     // [3,512]
    const float* __restrict__ Wh0,     // [128,512]
    const float* __restrict__ b0,      // [512]
    const float* __restrict__ tau0,    // [128]
    const float* __restrict__ s0,      // [128]
    const float* __restrict__ Wx1,     // [128,512]
    const float* __restrict__ Wh1,     // [128,512]
    const float* __restrict__ b1,      // [512]
    const float* __restrict__ tau1,    // [128]
    const float* __restrict__ s1,      // [128]
    const float* __restrict__ gamma_,  // [128]
    const float* __restrict__ beta_,   // [128]
    const float* __restrict__ Wfc,     // [128,10]
    const float* __restrict__ bfc,     // [10]
    float* __restrict__ out)           // [B,T,10]
{
    const int b = blockIdx.x;
    const int j = threadIdx.x;  // 0..511

    __shared__ __align__(16) float wh1s[WH1L * G4];  // 128 KB: Wh1 rows 0..63
    __shared__ __align__(16) float zs[G4];
    __shared__ __align__(16) float h0s[U];
    __shared__ __align__(16) float gh0s[U];          // gamma[u]*h0[u]
    __shared__ __align__(16) float h1s[U];
    __shared__ __align__(16) float wfcs[U * 11];     // stride 11: no bank aliasing
    __shared__ float bfcs[NCls];
    __shared__ float red[4];                         // {sum0,sq0,sum1,sq1}

    // ---- prologue: stage gamma/beta (temporarily in h0s/h1s), coop loads ----
    if (j < U) { h0s[j] = gamma_[j]; h1s[j] = beta_[j]; }
    {
        const float4* src = reinterpret_cast<const float4*>(Wh1);
        float4*       dst = reinterpret_cast<float4*>(wh1s);
        #pragma unroll
        for (int i = 0; i < (WH1L * G4 / 4) / 512; ++i)   // 16 float4 each
            dst[j + i * 512] = src[j + i * 512];
    }
    for (int i = j; i < U * NCls; i += 512) {
        const int u = i / NCls, c = i - u * NCls;
        wfcs[u * 11 + c] = Wfc[i];
    }
    if (j < NCls) bfcs[j] = bfc[j];
    __syncthreads();

    // ---- LayerNorm fold constants: P[j] = sum_u beta[u]*Wx1[u][j],
    //      Q[j] = sum_u gamma[u]*Wx1[u][j]  (one-time column read) ----
    float Pj = 0.0f, Qj = 0.0f;
    #pragma unroll 8
    for (int u = 0; u < U; ++u) {
        const float w = Wx1[u * G4 + j];
        Qj += h0s[u] * w;   // gamma staged in h0s
        Pj += h1s[u] * w;   // beta  staged in h1s
    }
    __syncthreads();

    if (j < U) { h0s[j] = 0.0f; h1s[j] = 0.0f; gh0s[j] = 0.0f; }

    // ---- per-thread persistent parameters ----
    const float bj0  = b0[j];
    const float bj1  = b1[j];
    const float wx00 = Wx0[j];
    const float wx01 = Wx0[G4 + j];
    const float wx02 = Wx0[2 * G4 + j];
    float tau0r = 0.f, s0r = 0.f, tau1r = 0.f, s1r = 0.f, gr = 0.f;
    if (j < U) {
        tau0r = tau0[j]; s0r = s0[j];
        tau1r = tau1[j]; s1r = s1[j];
        gr = gamma_[j];
    }
    float c0r = 0.f, c1r = 0.f, h0r = 0.f, h1r = 0.f;

    // ---- register-cache the full Wh0 column j (128 VGPRs) ----
    float4 wh0r[32];
    #pragma unroll
    for (int q = 0; q < 32; ++q) {
        wh0r[q].x = Wh0[(4*q+0)*G4 + j];
        wh0r[q].y = Wh0[(4*q+1)*G4 + j];
        wh0r[q].z = Wh0[(4*q+2)*G4 + j];
        wh0r[q].w = Wh0[(4*q+3)*G4 + j];
    }

    const float* __restrict__ xp   = inputs + (size_t)b * TSTEPS * 3;
    const float* __restrict__ tp   = times  + (size_t)b * TSTEPS;
    float*       __restrict__ op   = out    + (size_t)b * TSTEPS * NCls;
    const float* __restrict__ wx1p = Wx1 + j;
    const float* __restrict__ wh1p = Wh1 + j;

    float xa0 = xp[0], xa1 = xp[1], xa2 = xp[2], tva = tp[0];

    __syncthreads();

    for (int t = 0; t < TSTEPS; ++t) {
        const float x0 = xa0, x1 = xa1, x2 = xa2, tv = tva;

        float bufA[16], bufB[16], bufC[16];
        // prefetch first three streamed chunks (consumed after B2) + next x/t;
        // these stream from L2 during phases A/B.
        ISSUE(0, bufA);
        ISSUE(1, bufB);
        ISSUE(2, bufC);
        const int tn = (t + 1 < TSTEPS) ? t + 1 : t;
        xa0 = xp[tn*3+0]; xa1 = xp[tn*3+1]; xa2 = xp[tn*3+2]; tva = tp[tn];

        // ---- phase A: matvec0 (registers x LDS broadcast), 4 accumulators ----
        float a0 = bj0 + x0 * wx00, a1 = x1 * wx01, a2 = x2 * wx02, a3 = 0.0f;
        #pragma unroll
        for (int q = 0; q < 32; ++q) {
            const float4 h4 = *reinterpret_cast<const float4*>(&h0s[4*q]);
            a0 += h4.x * wh0r[q].x;
            a1 += h4.y * wh0r[q].y;
            a2 += h4.z * wh0r[q].z;
            a3 += h4.w * wh0r[q].w;
        }
        zs[j] = (a0 + a1) + (a2 + a3);
        __syncthreads();                                   // B1

        // ---- phase B: gates0 + LN partial sums (waves 0,1) ----
        if (j < U) {
            const float ig = sigm(zs[j]);
            const float fg = sigm(zs[j + U]);
            const float gg = tanhf(zs[j + 2*U]);
            const float og = sigm(zs[j + 3*U]);
            const float ch = fg * c0r + ig * gg;
            const float hh = og * tanhf(ch);
            const float k  = tgate(tv, tau0r, s0r);
            const float hn = k * hh + (1.0f - k) * h0r;
            c0r = k * ch + (1.0f - k) * c0r;
            h0r = hn;
            h0s[j]  = hn;
            gh0s[j] = gr * hn;
            float ssum = hn, qsum = hn * hn;               // one-pass variance
            #pragma unroll
            for (int off = 1; off < 64; off <<= 1) {
                ssum += __shfl_xor(ssum, off);
                qsum += __shfl_xor(qsum, off);
            }
            if ((j & 63) == 0) { red[(j >> 6)*2] = ssum; red[(j >> 6)*2 + 1] = qsum; }
        }
        __syncthreads();                                   // B2

        // ---- phase C: matvec1 with LN folded in ----
        const float mu   = (red[0] + red[2]) * (1.0f / 128.0f);
        const float msq  = (red[1] + red[3]) * (1.0f / 128.0f);
        const float rstd = rsqrtf(msq - mu * mu + 1e-3f);

        float ax0 = 0.f, ax1 = 0.f, ax2 = 0.f, ax3 = 0.f;  // Swx = sum (g*h0)*Wx1
        float ah0 = 0.f, ah1 = 0.f, ah2 = 0.f, ah3 = 0.f;  // Swh = sum h1*Wh1

        // LDS-cached Wh1 rows 0..63
        #pragma unroll
        for (int q = 0; q < 16; ++q) {
            const float4 h4 = *reinterpret_cast<const float4*>(&h1s[4*q]);
            ah0 += h4.x * wh1s[(4*q+0)*G4 + j];
            ah1 += h4.y * wh1s[(4*q+1)*G4 + j];
            ah2 += h4.z * wh1s[(4*q+2)*G4 + j];
            ah3 += h4.w * wh1s[(4*q+3)*G4 + j];
        }

        // streamed: 12 chunks, 3-deep register rotation
        CONSUME(0,  bufA);  ISSUE(3,  bufA);
        CONSUME(1,  bufB);  ISSUE(4,  bufB);
        CONSUME(2,  bufC);  ISSUE(5,  bufC);
        CONSUME(3,  bufA);  ISSUE(6,  bufA);
        CONSUME(4,  bufB);  ISSUE(7,  bufB);
        CONSUME(5,  bufC);  ISSUE(8,  bufC);
        CONSUME(6,  bufA);  ISSUE(9,  bufA);
        CONSUME(7,  bufB);  ISSUE(10, bufB);
        CONSUME(8,  bufC);  ISSUE(11, bufC);
        CONSUME(9,  bufA);
        CONSUME(10, bufB);
        CONSUME(11, bufC);

        const float Swx = (ax0 + ax1) + (ax2 + ax3);
        const float Swh = (ah0 + ah1) + (ah2 + ah3);
        // z1 = b1 + P + rstd*Swx - mu*rstd*Q + Swh   (exact LN fold)
        zs[j] = bj1 + Pj + rstd * Swx - (mu * rstd) * Qj + Swh;
        __syncthreads();                                   // B3

        // ---- phase D: gates1 (waves 0,1) ----
        if (j < U) {
            const float ig = sigm(zs[j]);
            const float fg = sigm(zs[j + U]);
            const float gg = tanhf(zs[j + 2*U]);
            const float og = sigm(zs[j + 3*U]);
            const float ch = fg * c1r + ig * gg;
            const float hh = og * tanhf(ch);
            const float k  = tgate(tv, tau1r, s1r);
            const float hn = k * hh + (1.0f - k) * h1r;
            c1r = k * ch + (1.0f - k) * c1r;
            h1r = hn;
            h1s[j] = hn;
        }
        __syncthreads();                                   // B4

        // ---- phase E: FC + softmax (wave 0); other waves roll into t+1 ----
        if (j < 64) {
            const float a  = h1s[j];
            const float bv = h1s[j + 64];
            float p[NCls];
            #pragma unroll
            for (int c = 0; c < NCls; ++c)
                p[c] = a * wfcs[j*11 + c] + bv * wfcs[(j+64)*11 + c];
            #pragma unroll
            for (int off = 1; off < 64; off <<= 1) {
                #pragma unroll
                for (int c = 0; c < NCls; ++c) p[c] += __shfl_xor(p[c], off);
            }
            float m = -1e30f;
            #pragma unroll
            for (int c = 0; c < NCls; ++c) { p[c] += bfcs[c]; m = fmaxf(m, p[c]); }
            float ssum = 0.0f;
            #pragma unroll
            for (int c = 0; c < NCls; ++c) { p[c] = __expf(p[c] - m); ssum += p[c]; }
            const float inv = 1.0f / ssum;
            float pv = p[0];                 // static-index select (no scratch)
            #pragma unroll
            for (int c = 1; c < NCls; ++c) if (j == c) pv = p[c];
            if (j < NCls) op[t * NCls + j] = pv * inv;
        }
    }
}

extern "C" void kernel_launch(void* const* d_in, const int* in_sizes, int n_in,
                              void* d_out, int out_size, void* d_ws, size_t ws_size,
                              hipStream_t stream) {
    const float* inputs = (const float*)d_in[0];
    const float* times  = (const float*)d_in[1];
    const float* Wx0    = (const float*)d_in[2];
    const float* Wh0    = (const float*)d_in[3];
    const float* b0     = (const float*)d_in[4];
    const float* tau0   = (const float*)d_in[5];
    const float* s0     = (const float*)d_in[6];
    const float* Wx1    = (const float*)d_in[7];
    const float* Wh1    = (const float*)d_in[8];
    const float* b1     = (const float*)d_in[9];
    const float* tau1   = (const float*)d_in[10];
    const float* s1     = (const float*)d_in[11];
    const float* gamma_ = (const float*)d_in[12];
    const float* beta_  = (const float*)d_in[13];
    const float* Wfc    = (const float*)d_in[14];
    const float* bfc    = (const float*)d_in[15];
    float* out = (float*)d_out;

    dim3 grid(BATCH);
    dim3 block(512);
    hipLaunchKernelGGL(plstm_fused, grid, block, 0, stream,
                       inputs, times, Wx0, Wh0, b0, tau0, s0,
                       Wx1, Wh1, b1, tau1, s1, gamma_, beta_, Wfc, bfc, out);
}

// Round 3
// 29447.198 us; speedup vs baseline: 1.0246x; 1.0246x over previous
//
#include <hip/hip_runtime.h>
#include <math.h>

// Problem constants (fixed by setup_inputs)
constexpr int U      = 128;   // UNITS
constexpr int G4     = 512;   // 4*U gate width
constexpr int NCls   = 10;    // classes
constexpr int TSTEPS = 1000;
constexpr int BATCH  = 256;

// ---------------------------------------------------------------------------
// VGPR budget lesson (rounds 1-2): the allocator caps this kernel at 128 VGPRs
// regardless of launch_bounds / amdgpu_waves_per_eu; any demand above that
// spills to scratch and thrashes L2 (47 GB HBM fetch). This version is built
// to fit 128 by construction:
//   - weight cache lives in LDS (Wh0 rows 0..63, 128 KB), not registers
//   - remaining 320 weight rows/step streamed from L2 through a 4-buffer
//     register rotation: 4 x 16 = 64 VGPRs, ~50 more for state -> ~115 total
// Stream chunk map (16 rows each):
//   chunks  0..7  = Wx1 rows 0..127   (consumed phase C with gh0s)
//   chunks  8..15 = Wh1 rows 0..127   (consumed phase C with h1s)
//   chunks 16..19 = Wh0 rows 64..127  (consumed NEXT step phase A with h0s)
// Buffer = chunk % 4. Issue happens at the consume of chunk-4 (>= 4 slots of
// slack; chunks 16..19 get a whole phase-D/E + loop-back of slack).
// ---------------------------------------------------------------------------

__device__ __forceinline__ float sigm(float x) {
    return 1.0f / (1.0f + __expf(-x));
}

// k = time_gate(t, tau, s); floor-mod semantics matching jnp.mod
__device__ __forceinline__ float tgate(float t, float tau, float s) {
    float r = fmodf(t - s, tau);
    if (r < 0.0f) r += tau;
    const float phi = r / tau;
    return (phi < 0.025f) ? 40.0f * phi
         : (phi < 0.05f)  ? 2.0f - 40.0f * phi
         : 0.001f * phi;
}

// Issue 16 streamed weight loads for compile-time chunk K into register BUF.
// Uniform matrix base + (const*G4 + j) index -> saddr+voffset codegen.
#define ISSUE(K, BUF) { \
    _Pragma("unroll") \
    for (int ii = 0; ii < 16; ++ii) { \
        if ((K) < 8)       (BUF)[ii] = Wx1[((K) * 16 + ii) * G4 + j]; \
        else if ((K) < 16) (BUF)[ii] = Wh1[(((K) - 8) * 16 + ii) * G4 + j]; \
        else               (BUF)[ii] = Wh0[(64 + ((K) - 16) * 16 + ii) * G4 + j]; \
    } }

// Phase-C consumes: Wx1 chunks (gh0s broadcast) accumulate into ax*,
// Wh1 chunks (h1s broadcast) into ah* (kept separate for the LN fold).
#define CONSUME_X(K, BUF) { \
    _Pragma("unroll") \
    for (int q = 0; q < 4; ++q) { \
        const float4 g4_ = *reinterpret_cast<const float4*>(&gh0s[16*(K) + 4*q]); \
        ax0 += g4_.x * (BUF)[4*q+0]; \
        ax1 += g4_.y * (BUF)[4*q+1]; \
        ax2 += g4_.z * (BUF)[4*q+2]; \
        ax3 += g4_.w * (BUF)[4*q+3]; \
    } }

#define CONSUME_H(K, BUF) { \
    _Pragma("unroll") \
    for (int q = 0; q < 4; ++q) { \
        const float4 h4_ = *reinterpret_cast<const float4*>(&h1s[16*((K)-8) + 4*q]); \
        ah0 += h4_.x * (BUF)[4*q+0]; \
        ah1 += h4_.y * (BUF)[4*q+1]; \
        ah2 += h4_.z * (BUF)[4*q+2]; \
        ah3 += h4_.w * (BUF)[4*q+3]; \
    } }

// Phase-A consume of streamed Wh0 rows 64..127 (h0s upper broadcast).
#define CONSUME_A(K, BUF) { \
    _Pragma("unroll") \
    for (int q = 0; q < 4; ++q) { \
        const float4 h4_ = *reinterpret_cast<const float4*>(&h0s[64 + 16*((K)-16) + 4*q]); \
        a0 += h4_.x * (BUF)[4*q+0]; \
        a1 += h4_.y * (BUF)[4*q+1]; \
        a2 += h4_.z * (BUF)[4*q+2]; \
        a3 += h4_.w * (BUF)[4*q+3]; \
    } }

// Phase-A consume of 4 LDS-cached Wh0 rows (rows 4Q..4Q+3, Q = 0..15).
#define CACHED4(Q) { \
    const float4 h4_ = *reinterpret_cast<const float4*>(&h0s[4*(Q)]); \
    a0 += h4_.x * wh0c[(4*(Q)+0)*G4 + j]; \
    a1 += h4_.y * wh0c[(4*(Q)+1)*G4 + j]; \
    a2 += h4_.z * wh0c[(4*(Q)+2)*G4 + j]; \
    a3 += h4_.w * wh0c[(4*(Q)+3)*G4 + j]; }

__global__ __launch_bounds__(512, 2) void plstm_fused(
    const float* __restrict__ inputs,  // [B,T,3]
    const float* __restrict__ times,   // [B,T]
    const float* __restrict__ Wx0,     // [3,512]
    const float* __restrict__ Wh0,     // [128,512]
    const float* __restrict__ b0,      // [512]
    const float* __restrict__ tau0,    // [128]
    const float* __restrict__ s0,      // [128]
    const float* __restrict__ Wx1,     // [128,512]
    const float* __restrict__ Wh1,     // [128,512]
    const float* __restrict__ b1,      // [512]
    const float* __restrict__ tau1,    // [128]
    const float* __restrict__ s1,      // [128]
    const float* __restrict__ gamma_,  // [128]
    const float* __restrict__ beta_,   // [128]
    const float* __restrict__ Wfc,     // [128,10]
    const float* __restrict__ bfc,     // [10]
    float* __restrict__ out)           // [B,T,10]
{
    const int b = blockIdx.x;
    const int j = threadIdx.x;  // 0..511

    __shared__ __align__(16) float wh0c[64 * G4];    // 128 KB: Wh0 rows 0..63
    __shared__ __align__(16) float zs[G4];
    __shared__ __align__(16) float h0s[U];
    __shared__ __align__(16) float gh0s[U];          // gamma[u]*h0[u]
    __shared__ __align__(16) float h1s[U];
    __shared__ __align__(16) float wfcs[U * 11];     // stride 11: no bank aliasing
    __shared__ float bfcs[NCls];
    __shared__ float red[4];                         // {sum0,sq0,sum1,sq1}

    // ---- prologue: stage gamma/beta (temporarily in h0s/h1s), coop loads ----
    if (j < U) { h0s[j] = gamma_[j]; h1s[j] = beta_[j]; }
    {
        // Wh0 rows 0..63 -> LDS (8192 float4, 16 per thread)
        const float4* src = reinterpret_cast<const float4*>(Wh0);
        float4*       dst = reinterpret_cast<float4*>(wh0c);
        #pragma unroll
        for (int i = 0; i < 16; ++i)
            dst[j + i * 512] = src[j + i * 512];
    }
    for (int i = j; i < U * NCls; i += 512) {
        const int u = i / NCls, c = i - u * NCls;
        wfcs[u * 11 + c] = Wfc[i];
    }
    if (j < NCls) bfcs[j] = bfc[j];
    __syncthreads();

    // ---- LayerNorm fold constants: P[j] = sum_u beta[u]*Wx1[u][j],
    //      Q[j] = sum_u gamma[u]*Wx1[u][j]  (one-time column read) ----
    float Pj = 0.0f, Qj = 0.0f;
    #pragma unroll 8
    for (int u = 0; u < U; ++u) {
        const float w = Wx1[u * G4 + j];
        Qj += h0s[u] * w;   // gamma staged in h0s
        Pj += h1s[u] * w;   // beta  staged in h1s
    }
    __syncthreads();

    if (j < U) { h0s[j] = 0.0f; h1s[j] = 0.0f; gh0s[j] = 0.0f; }

    // ---- per-thread persistent parameters ----
    const float bj0  = b0[j];
    const float bj1  = b1[j];
    const float wx00 = Wx0[j];
    const float wx01 = Wx0[G4 + j];
    const float wx02 = Wx0[2 * G4 + j];
    float tau0r = 0.f, s0r = 0.f, tau1r = 0.f, s1r = 0.f, gr = 0.f;
    if (j < U) {
        tau0r = tau0[j]; s0r = s0[j];
        tau1r = tau1[j]; s1r = s1[j];
        gr = gamma_[j];
    }
    float c0r = 0.f, c1r = 0.f, h0r = 0.f, h1r = 0.f;

    const float* __restrict__ xp = inputs + (size_t)b * TSTEPS * 3;
    const float* __restrict__ tp = times  + (size_t)b * TSTEPS;
    float*       __restrict__ op = out    + (size_t)b * TSTEPS * NCls;

    float xa0 = xp[0], xa1 = xp[1], xa2 = xp[2], tva = tp[0];

    // ---- stream pipeline prologue: chunks 16..19 (phase A of t=0) ----
    float bufA[16], bufB[16], bufC[16], bufD[16];
    ISSUE(16, bufA);
    ISSUE(17, bufB);
    ISSUE(18, bufC);
    ISSUE(19, bufD);

    __syncthreads();

    for (int t = 0; t < TSTEPS; ++t) {
        const float x0 = xa0, x1 = xa1, x2 = xa2, tv = tva;
        const int tn = (t + 1 < TSTEPS) ? t + 1 : t;
        xa0 = xp[tn*3+0]; xa1 = xp[tn*3+1]; xa2 = xp[tn*3+2]; tva = tp[tn];

        // ---- phase A: matvec0 = LDS-cached rows 0..63 + streamed 64..127 ----
        float a0 = bj0 + x0 * wx00, a1 = x1 * wx01, a2 = x2 * wx02, a3 = 0.0f;
        CONSUME_A(16, bufA);  ISSUE(0, bufA);
        CACHED4(0);  CACHED4(1);  CACHED4(2);  CACHED4(3);
        CONSUME_A(17, bufB);  ISSUE(1, bufB);
        CACHED4(4);  CACHED4(5);  CACHED4(6);  CACHED4(7);
        CONSUME_A(18, bufC);  ISSUE(2, bufC);
        CACHED4(8);  CACHED4(9);  CACHED4(10); CACHED4(11);
        CONSUME_A(19, bufD);  ISSUE(3, bufD);
        CACHED4(12); CACHED4(13); CACHED4(14); CACHED4(15);
        zs[j] = (a0 + a1) + (a2 + a3);
        __syncthreads();                                   // B1

        // ---- phase B: gates0 + LN partial sums (waves 0,1) ----
        if (j < U) {
            const float ig = sigm(zs[j]);
            const float fg = sigm(zs[j + U]);
            const float gg = tanhf(zs[j + 2*U]);
            const float og = sigm(zs[j + 3*U]);
            const float ch = fg * c0r + ig * gg;
            const float hh = og * tanhf(ch);
            const float k  = tgate(tv, tau0r, s0r);
            const float hn = k * hh + (1.0f - k) * h0r;
            c0r = k * ch + (1.0f - k) * c0r;
            h0r = hn;
            h0s[j]  = hn;
            gh0s[j] = gr * hn;
            float ssum = hn, qsum = hn * hn;               // one-pass variance
            #pragma unroll
            for (int off = 1; off < 64; off <<= 1) {
                ssum += __shfl_xor(ssum, off);
                qsum += __shfl_xor(qsum, off);
            }
            if ((j & 63) == 0) { red[(j >> 6)*2] = ssum; red[(j >> 6)*2 + 1] = qsum; }
        }
        __syncthreads();                                   // B2

        // ---- phase C: matvec1 (fully streamed) with LN folded in ----
        const float mu   = (red[0] + red[2]) * (1.0f / 128.0f);
        const float msq  = (red[1] + red[3]) * (1.0f / 128.0f);
        const float rstd = rsqrtf(msq - mu * mu + 1e-3f);

        float ax0 = 0.f, ax1 = 0.f, ax2 = 0.f, ax3 = 0.f;  // Swx = sum (g*h0)*Wx1
        float ah0 = 0.f, ah1 = 0.f, ah2 = 0.f, ah3 = 0.f;  // Swh = sum h1*Wh1

        CONSUME_X(0,  bufA);  ISSUE(4,  bufA);
        CONSUME_X(1,  bufB);  ISSUE(5,  bufB);
        CONSUME_X(2,  bufC);  ISSUE(6,  bufC);
        CONSUME_X(3,  bufD);  ISSUE(7,  bufD);
        CONSUME_X(4,  bufA);  ISSUE(8,  bufA);
        CONSUME_X(5,  bufB);  ISSUE(9,  bufB);
        CONSUME_X(6,  bufC);  ISSUE(10, bufC);
        CONSUME_X(7,  bufD);  ISSUE(11, bufD);
        CONSUME_H(8,  bufA);  ISSUE(12, bufA);
        CONSUME_H(9,  bufB);  ISSUE(13, bufB);
        CONSUME_H(10, bufC);  ISSUE(14, bufC);
        CONSUME_H(11, bufD);  ISSUE(15, bufD);
        CONSUME_H(12, bufA);  ISSUE(16, bufA);   // 16..19: next step's phase A
        CONSUME_H(13, bufB);  ISSUE(17, bufB);
        CONSUME_H(14, bufC);  ISSUE(18, bufC);
        CONSUME_H(15, bufD);  ISSUE(19, bufD);

        const float Swx = (ax0 + ax1) + (ax2 + ax3);
        const float Swh = (ah0 + ah1) + (ah2 + ah3);
        // z1 = b1 + P + rstd*Swx - mu*rstd*Q + Swh   (exact LN fold)
        zs[j] = bj1 + Pj + rstd * Swx - (mu * rstd) * Qj + Swh;
        __syncthreads();                                   // B3

        // ---- phase D: gates1 (waves 0,1) ----
        if (j < U) {
            const float ig = sigm(zs[j]);
            const float fg = sigm(zs[j + U]);
            const float gg = tanhf(zs[j + 2*U]);
            const float og = sigm(zs[j + 3*U]);
            const float ch = fg * c1r + ig * gg;
            const float hh = og * tanhf(ch);
            const float k  = tgate(tv, tau1r, s1r);
            const float hn = k * hh + (1.0f - k) * h1r;
            c1r = k * ch + (1.0f - k) * c1r;
            h1r = hn;
            h1s[j] = hn;
        }
        __syncthreads();                                   // B4

        // ---- phase E: FC + softmax (wave 0); other waves roll into t+1 ----
        if (j < 64) {
            const float a  = h1s[j];
            const float bv = h1s[j + 64];
            float p[NCls];
            #pragma unroll
            for (int c = 0; c < NCls; ++c)
                p[c] = a * wfcs[j*11 + c] + bv * wfcs[(j+64)*11 + c];
            #pragma unroll
            for (int off = 1; off < 64; off <<= 1) {
                #pragma unroll
                for (int c = 0; c < NCls; ++c) p[c] += __shfl_xor(p[c], off);
            }
            float m = -1e30f;
            #pragma unroll
            for (int c = 0; c < NCls; ++c) { p[c] += bfcs[c]; m = fmaxf(m, p[c]); }
            float ssum = 0.0f;
            #pragma unroll
            for (int c = 0; c < NCls; ++c) { p[c] = __expf(p[c] - m); ssum += p[c]; }
            const float inv = 1.0f / ssum;
            float pv = p[0];                 // static-index select (no scratch)
            #pragma unroll
            for (int c = 1; c < NCls; ++c) if (j == c) pv = p[c];
            if (j < NCls) op[t * NCls + j] = pv * inv;
        }
    }
}

extern "C" void kernel_launch(void* const* d_in, const int* in_sizes, int n_in,
                              void* d_out, int out_size, void* d_ws, size_t ws_size,
                              hipStream_t stream) {
    const float* inputs = (const float*)d_in[0];
    const float* times  = (const float*)d_in[1];
    const float* Wx0    = (const float*)d_in[2];
    const float* Wh0    = (const float*)d_in[3];
    const float* b0     = (const float*)d_in[4];
    const float* tau0   = (const float*)d_in[5];
    const float* s0     = (const float*)d_in[6];
    const float* Wx1    = (const float*)d_in[7];
    const float* Wh1    = (const float*)d_in[8];
    const float* b1     = (const float*)d_in[9];
    const float* tau1   = (const float*)d_in[10];
    const float* s1     = (const float*)d_in[11];
    const float* gamma_ = (const float*)d_in[12];
    const float* beta_  = (const float*)d_in[13];
    const float* Wfc    = (const float*)d_in[14];
    const float* bfc    = (const float*)d_in[15];
    float* out = (float*)d_out;

    dim3 grid(BATCH);
    dim3 block(512);
    hipLaunchKernelGGL(plstm_fused, grid, block, 0, stream,
                       inputs, times, Wx0, Wh0, b0, tau0, s0,
                       Wx1, Wh1, b1, tau1, s1, gamma_, beta_, Wfc, bfc, out);
}

// Round 4
// 8565.668 us; speedup vs baseline: 3.5225x; 3.4378x over previous
//
#include <hip/hip_runtime.h>
#include <math.h>

// Problem constants (fixed by setup_inputs)
constexpr int U      = 128;   // UNITS
constexpr int G4     = 512;   // 4*U gate width
constexpr int NCls   = 10;    // classes
constexpr int TSTEPS = 1000;
constexpr int BATCH  = 256;

// ---------------------------------------------------------------------------
// Lessons burned in (rounds 1-3): any "streaming" scheme that issues weight
// loads far ahead of use across barriers (register rotation, 4-buffer
// pipelines) blows up HBM FETCH to ~50 GB and halves throughput vs the naive
// pattern. The per-use load pattern below keeps all three weight matrices
// (768 KB) L2-resident (46 MB HBM total, measured round 0). This version is
// round-0's memory pattern + the safe wins verified since:
//   - 4 independent accumulators per matvec (round 0 had a single dependent
//     FMA chain: 384 x 4cyc of un-hideable latency per step)
//   - unroll 8 on matvec0 / 4 on matvec1 -> ~32 outstanding L2 loads
//   - LayerNorm folded into matvec1 (Pj/Qj identity; removes the hn
//     materialization phase and one barrier; verified absmax-identical)
//   - x/t prefetch, Wfc in stride-11 LDS, 4 barriers/step, FC/softmax on
//     wave 0 overlapping the next step's matvec0
// VGPR demand ~80 << 128 cap: no spill possible by construction.
// ---------------------------------------------------------------------------

__device__ __forceinline__ float sigm(float x) {
    return 1.0f / (1.0f + __expf(-x));
}

// k = time_gate(t, tau, s); floor-mod semantics matching jnp.mod
__device__ __forceinline__ float tgate(float t, float tau, float s) {
    float r = fmodf(t - s, tau);
    if (r < 0.0f) r += tau;
    const float phi = r / tau;
    return (phi < 0.025f) ? 40.0f * phi
         : (phi < 0.05f)  ? 2.0f - 40.0f * phi
         : 0.001f * phi;
}

__global__ __launch_bounds__(512, 1) void plstm_fused(
    const float* __restrict__ inputs,  // [B,T,3]
    const float* __restrict__ times,   // [B,T]
    const float* __restrict__ Wx0,     // [3,512]
    const float* __restrict__ Wh0,     // [128,512]
    const float* __restrict__ b0,      // [512]
    const float* __restrict__ tau0,    // [128]
    const float* __restrict__ s0,      // [128]
    const float* __restrict__ Wx1,     // [128,512]
    const float* __restrict__ Wh1,     // [128,512]
    const float* __restrict__ b1,      // [512]
    const float* __restrict__ tau1,    // [128]
    const float* __restrict__ s1,      // [128]
    const float* __restrict__ gamma_,  // [128]
    const float* __restrict__ beta_,   // [128]
    const float* __restrict__ Wfc,     // [128,10]
    const float* __restrict__ bfc,     // [10]
    float* __restrict__ out)           // [B,T,10]
{
    const int b = blockIdx.x;
    const int j = threadIdx.x;  // 0..511

    __shared__ __align__(16) float zs[G4];
    __shared__ __align__(16) float h0s[U];
    __shared__ __align__(16) float gh0s[U];          // gamma[u]*h0[u]
    __shared__ __align__(16) float h1s[U];
    __shared__ __align__(16) float wfcs[U * 11];     // stride 11: no bank aliasing
    __shared__ float bfcs[NCls];
    __shared__ float red[4];                         // {sum0,sq0,sum1,sq1}

    // ---- prologue: stage gamma/beta (temporarily in h0s/h1s), coop loads ----
    if (j < U) { h0s[j] = gamma_[j]; h1s[j] = beta_[j]; }
    for (int i = j; i < U * NCls; i += 512) {
        const int u = i / NCls, c = i - u * NCls;
        wfcs[u * 11 + c] = Wfc[i];
    }
    if (j < NCls) bfcs[j] = bfc[j];
    __syncthreads();

    // ---- LayerNorm fold constants: P[j] = sum_u beta[u]*Wx1[u][j],
    //      Q[j] = sum_u gamma[u]*Wx1[u][j]  (one-time column read) ----
    float Pj = 0.0f, Qj = 0.0f;
    #pragma unroll 8
    for (int u = 0; u < U; ++u) {
        const float w = Wx1[u * G4 + j];
        Qj += h0s[u] * w;   // gamma staged in h0s
        Pj += h1s[u] * w;   // beta  staged in h1s
    }
    __syncthreads();

    if (j < U) { h0s[j] = 0.0f; h1s[j] = 0.0f; gh0s[j] = 0.0f; }

    // ---- per-thread persistent parameters ----
    const float bj0  = b0[j];
    const float bj1  = b1[j];
    const float wx00 = Wx0[j];
    const float wx01 = Wx0[G4 + j];
    const float wx02 = Wx0[2 * G4 + j];
    float tau0r = 0.f, s0r = 0.f, tau1r = 0.f, s1r = 0.f, gr = 0.f;
    if (j < U) {
        tau0r = tau0[j]; s0r = s0[j];
        tau1r = tau1[j]; s1r = s1[j];
        gr = gamma_[j];
    }
    float c0r = 0.f, c1r = 0.f, h0r = 0.f, h1r = 0.f;

    // Per-thread column bases (saddr + small imm offsets in codegen)
    const float* __restrict__ wh0p = Wh0 + j;
    const float* __restrict__ wx1p = Wx1 + j;
    const float* __restrict__ wh1p = Wh1 + j;
    const float* __restrict__ xp   = inputs + (size_t)b * TSTEPS * 3;
    const float* __restrict__ tp   = times  + (size_t)b * TSTEPS;
    float*       __restrict__ op   = out    + (size_t)b * TSTEPS * NCls;

    float xa0 = xp[0], xa1 = xp[1], xa2 = xp[2], tva = tp[0];

    __syncthreads();

    for (int t = 0; t < TSTEPS; ++t) {
        const float x0 = xa0, x1 = xa1, x2 = xa2, tv = tva;
        const int tn = (t + 1 < TSTEPS) ? t + 1 : t;
        xa0 = xp[tn*3+0]; xa1 = xp[tn*3+1]; xa2 = xp[tn*3+2]; tva = tp[tn];

        // ---- phase A: matvec0, per-use L2 loads, 4 accumulators ----
        float a0 = bj0 + x0 * wx00, a1 = x1 * wx01, a2 = x2 * wx02, a3 = 0.0f;
        #pragma unroll 8
        for (int u = 0; u < U; u += 4) {
            const float4 h4 = *reinterpret_cast<const float4*>(&h0s[u]);
            a0 += h4.x * wh0p[(u + 0) * G4];
            a1 += h4.y * wh0p[(u + 1) * G4];
            a2 += h4.z * wh0p[(u + 2) * G4];
            a3 += h4.w * wh0p[(u + 3) * G4];
        }
        zs[j] = (a0 + a1) + (a2 + a3);
        __syncthreads();                                   // B1

        // ---- phase B: gates0 + LN partial sums (waves 0,1) ----
        if (j < U) {
            const float ig = sigm(zs[j]);
            const float fg = sigm(zs[j + U]);
            const float gg = tanhf(zs[j + 2*U]);
            const float og = sigm(zs[j + 3*U]);
            const float ch = fg * c0r + ig * gg;
            const float hh = og * tanhf(ch);
            const float k  = tgate(tv, tau0r, s0r);
            const float hn = k * hh + (1.0f - k) * h0r;
            c0r = k * ch + (1.0f - k) * c0r;
            h0r = hn;
            h0s[j]  = hn;
            gh0s[j] = gr * hn;
            float ssum = hn, qsum = hn * hn;               // one-pass variance
            #pragma unroll
            for (int off = 1; off < 64; off <<= 1) {
                ssum += __shfl_xor(ssum, off);
                qsum += __shfl_xor(qsum, off);
            }
            if ((j & 63) == 0) { red[(j >> 6)*2] = ssum; red[(j >> 6)*2 + 1] = qsum; }
        }
        __syncthreads();                                   // B2

        // ---- phase C: matvec1 with LN folded in, per-use L2 loads ----
        const float mu   = (red[0] + red[2]) * (1.0f / 128.0f);
        const float msq  = (red[1] + red[3]) * (1.0f / 128.0f);
        const float rstd = rsqrtf(msq - mu * mu + 1e-3f);

        float ax0 = 0.f, ax1 = 0.f, ax2 = 0.f, ax3 = 0.f;  // Swx = sum (g*h0)*Wx1
        float ah0 = 0.f, ah1 = 0.f, ah2 = 0.f, ah3 = 0.f;  // Swh = sum h1*Wh1
        #pragma unroll 4
        for (int u = 0; u < U; u += 4) {
            const float4 g4 = *reinterpret_cast<const float4*>(&gh0s[u]);
            const float4 h4 = *reinterpret_cast<const float4*>(&h1s[u]);
            ax0 += g4.x * wx1p[(u + 0) * G4];  ah0 += h4.x * wh1p[(u + 0) * G4];
            ax1 += g4.y * wx1p[(u + 1) * G4];  ah1 += h4.y * wh1p[(u + 1) * G4];
            ax2 += g4.z * wx1p[(u + 2) * G4];  ah2 += h4.z * wh1p[(u + 2) * G4];
            ax3 += g4.w * wx1p[(u + 3) * G4];  ah3 += h4.w * wh1p[(u + 3) * G4];
        }
        const float Swx = (ax0 + ax1) + (ax2 + ax3);
        const float Swh = (ah0 + ah1) + (ah2 + ah3);
        // z1 = b1 + P + rstd*Swx - mu*rstd*Q + Swh   (exact LN fold)
        zs[j] = bj1 + Pj + rstd * Swx - (mu * rstd) * Qj + Swh;
        __syncthreads();                                   // B3

        // ---- phase D: gates1 (waves 0,1) ----
        if (j < U) {
            const float ig = sigm(zs[j]);
            const float fg = sigm(zs[j + U]);
            const float gg = tanhf(zs[j + 2*U]);
            const float og = sigm(zs[j + 3*U]);
            const float ch = fg * c1r + ig * gg;
            const float hh = og * tanhf(ch);
            const float k  = tgate(tv, tau1r, s1r);
            const float hn = k * hh + (1.0f - k) * h1r;
            c1r = k * ch + (1.0f - k) * c1r;
            h1r = hn;
            h1s[j] = hn;
        }
        __syncthreads();                                   // B4

        // ---- phase E: FC + softmax (wave 0); other waves roll into t+1 ----
        if (j < 64) {
            const float a  = h1s[j];
            const float bv = h1s[j + 64];
            float p[NCls];
            #pragma unroll
            for (int c = 0; c < NCls; ++c)
                p[c] = a * wfcs[j*11 + c] + bv * wfcs[(j+64)*11 + c];
            #pragma unroll
            for (int off = 1; off < 64; off <<= 1) {
                #pragma unroll
                for (int c = 0; c < NCls; ++c) p[c] += __shfl_xor(p[c], off);
            }
            float m = -1e30f;
            #pragma unroll
            for (int c = 0; c < NCls; ++c) { p[c] += bfcs[c]; m = fmaxf(m, p[c]); }
            float ssum = 0.0f;
            #pragma unroll
            for (int c = 0; c < NCls; ++c) { p[c] = __expf(p[c] - m); ssum += p[c]; }
            const float inv = 1.0f / ssum;
            float pv = p[0];                 // static-index select (no scratch)
            #pragma unroll
            for (int c = 1; c < NCls; ++c) if (j == c) pv = p[c];
            if (j < NCls) op[t * NCls + j] = pv * inv;
        }
        // No trailing barrier: next hazard (zs write in phase A) is fenced by
        // B1, and wave 0's phase-E work overlaps the other waves' matvec0.
    }
}

extern "C" void kernel_launch(void* const* d_in, const int* in_sizes, int n_in,
                              void* d_out, int out_size, void* d_ws, size_t ws_size,
                              hipStream_t stream) {
    const float* inputs = (const float*)d_in[0];
    const float* times  = (const float*)d_in[1];
    const float* Wx0    = (const float*)d_in[2];
    const float* Wh0    = (const float*)d_in[3];
    const float* b0     = (const float*)d_in[4];
    const float* tau0   = (const float*)d_in[5];
    const float* s0     = (const float*)d_in[6];
    const float* Wx1    = (const float*)d_in[7];
    const float* Wh1    = (const float*)d_in[8];
    const float* b1     = (const float*)d_in[9];
    const float* tau1   = (const float*)d_in[10];
    const float* s1     = (const float*)d_in[11];
    const float* gamma_ = (const float*)d_in[12];
    const float* beta_  = (const float*)d_in[13];
    const float* Wfc    = (const float*)d_in[14];
    const float* bfc    = (const float*)d_in[15];
    float* out = (float*)d_out;

    dim3 grid(BATCH);
    dim3 block(512);
    hipLaunchKernelGGL(plstm_fused, grid, block, 0, stream,
                       inputs, times, Wx0, Wh0, b0, tau0, s0,
                       Wx1, Wh1, b1, tau1, s1, gamma_, beta_, Wfc, bfc, out);
}